// Round 10
// baseline (2183.484 us; speedup 1.0000x reference)
//
#include <hip/hip_runtime.h>
#include <hip/hip_fp16.h>
#include <math.h>

#define NT8 512
#define NT  1024

typedef _Float16 h2v __attribute__((ext_vector_type(2)));
union H8 { uint4 u; h2v h[4]; };

__device__ __forceinline__ float sigf(float x)   { return 1.0f / (1.0f + __expf(-x)); }
__device__ __forceinline__ float tanhf_(float x) { return 1.0f - 2.0f / (1.0f + __expf(2.0f * x)); }
__device__ __forceinline__ float dot4(float4 a, float4 b) {
    return a.x * b.x + a.y * b.y + a.z * b.z + a.w * b.w;
}
__device__ __forceinline__ float red16(float v) {
    v += __shfl_xor(v, 1); v += __shfl_xor(v, 2);
    v += __shfl_xor(v, 4); v += __shfl_xor(v, 8);
    return v;
}
__device__ __forceinline__ float red8(float v) {
    v += __shfl_xor(v, 1); v += __shfl_xor(v, 2); v += __shfl_xor(v, 4);
    return v;
}
__device__ __forceinline__ float red64(float v) {
    v += __shfl_xor(v, 1);  v += __shfl_xor(v, 2);  v += __shfl_xor(v, 4);
    v += __shfl_xor(v, 8);  v += __shfl_xor(v, 16); v += __shfl_xor(v, 32);
    return v;
}
__device__ __forceinline__ float dot2h(h2v a, h2v b, float c) {
#if __has_builtin(__builtin_amdgcn_fdot2)
    return __builtin_amdgcn_fdot2(a, b, c, false);
#else
    return c + (float)a[0] * (float)b[0] + (float)a[1] * (float)b[1];
#endif
}

// LLC-coherent load / store (bypass L1/L2; no cache flush). v6-proven loads;
// stores are relaxed agent-scope atomic stores (sc1 write-through, pipelined,
// no RMW serialization at the LLC bank).
__device__ __forceinline__ float exr(const float* p) {
    return __hip_atomic_load(p, __ATOMIC_RELAXED, __HIP_MEMORY_SCOPE_AGENT);
}
__device__ __forceinline__ void exw(float* p, float v) {
    __hip_atomic_store(p, v, __ATOMIC_RELAXED, __HIP_MEMORY_SCOPE_AGENT);
}
// Split fence-free group barrier. Writers may be in ANY wave now, so every
// thread drains its own wave's vmcnt before the block-wide sync; then tid0
// signals. Readers poll relaxed agent loads (v6 mechanism).
__device__ __forceinline__ void xsig(unsigned* ctr) {
    asm volatile("s_waitcnt vmcnt(0)" ::: "memory");
    __syncthreads();
    if (threadIdx.x == 0)
        __hip_atomic_fetch_add(ctr, 1u, __ATOMIC_RELAXED, __HIP_MEMORY_SCOPE_AGENT);
}
__device__ __forceinline__ void xwait(unsigned* ctr, unsigned target) {
    if (threadIdx.x == 0) {
        while (__hip_atomic_load(ctr, __ATOMIC_RELAXED, __HIP_MEMORY_SCOPE_AGENT) < target)
            __builtin_amdgcn_s_sleep(1);
    }
    __syncthreads();
}

// ws half-offsets (permuted-packed fp16 weights)
#define OFF_RA   0          // aw1[:, 0:512]          64 x 512   (v5 fallback)
#define OFF_RE0  32768      // [wihe0|whhe0|pad]      1024 x 384
#define OFF_RE1  425984     // [wihe1|whhe1]          1024 x 512
#define OFF_RDW1 950272     // dw1[:, 0:512]          256 x 512  (v5 fallback)
#define OFF_RD0  1081344    // [wihd0[:,0:256]|whhd0] 1024 x 512
#define OFF_RDT  1605632    // wihd0[:, 256]          1024
#define OFF_RD1  1606656    // [wihd1|whhd1]          1024 x 512
#define OFF_RPD  2130944    // dw1[:, 512:768]        256 x 256 (Pd tile)
#define OFF_RAC  2196480    // col-split aw1: [co][64 rows][64 cols]
#define OFF_RDWC 2229248    // col-split dw1: [co][256 rows][64 cols]
#define TOT_H3   2360320

// ---------------- v9 GEMV helpers (NT8=512: 8 waves) ----------------
// Row-split K=512: wave w owns local rows l = w*16 + it*4 + g (l<128);
// global j = ((l&0x60)<<3) + coB + (l&31).
template<int ITERS, bool BIAS, bool DT>
__device__ __forceinline__ void gemvS512(const __half* __restrict__ W,
                                         const __half* __restrict__ act,
                                         const float* __restrict__ biasF,
                                         const __half* __restrict__ rdtH, float dts,
                                         float* __restrict__ outg, int coB) {
    const int lane = threadIdx.x & 63;
    const int q = lane & 15, g = lane >> 4;
    const int w = threadIdx.x >> 6;
    H8 a0, a1, a2, a3;
    a0.u = *(const uint4*)(act + 8 * q);
    a1.u = *(const uint4*)(act + 8 * q + 128);
    a2.u = *(const uint4*)(act + 8 * q + 256);
    a3.u = *(const uint4*)(act + 8 * q + 384);
    #pragma unroll 2
    for (int it = 0; it < ITERS; ++it) {
        const int l = w * 16 + it * 4 + g;
        const int j = ((l & 0x60) << 3) + coB + (l & 31);
        const uint4* wp = (const uint4*)(W + ((size_t)j << 9) + 32 * q);
        H8 w0, w1, w2, w3;
        w0.u = wp[0]; w1.u = wp[1]; w2.u = wp[2]; w3.u = wp[3];
        float s0 = 0.f, s1 = 0.f;
        #pragma unroll
        for (int i = 0; i < 4; ++i) {
            s0 = dot2h(w0.h[i], a0.h[i], s0);
            s1 = dot2h(w1.h[i], a1.h[i], s1);
            s0 = dot2h(w2.h[i], a2.h[i], s0);
            s1 = dot2h(w3.h[i], a3.h[i], s1);
        }
        float s = red16(s0 + s1);
        if (q == 0) {
            if (DT) s += dts * (float)rdtH[l];
            outg[l] = BIAS ? s + biasF[l] : s;
        }
    }
}

// Row-split K=384 (encoder layer0)
template<int ITERS>
__device__ __forceinline__ void gemvS384(const __half* __restrict__ W,
                                         const __half* __restrict__ act,
                                         const float* __restrict__ biasF,
                                         float* __restrict__ outg, int coB) {
    const int lane = threadIdx.x & 63;
    const int q = lane & 15, g = lane >> 4;
    const int w = threadIdx.x >> 6;
    H8 a0, a1, a2;
    a0.u = *(const uint4*)(act + 8 * q);
    a1.u = *(const uint4*)(act + 8 * q + 128);
    a2.u = *(const uint4*)(act + 8 * q + 256);
    #pragma unroll 2
    for (int it = 0; it < ITERS; ++it) {
        const int l = w * 16 + it * 4 + g;
        const int j = ((l & 0x60) << 3) + coB + (l & 31);
        const h2v* hp = (const h2v*)(W + (size_t)j * 384 + 24 * q);
        float s0 = 0.f, s1 = 0.f;
        #pragma unroll
        for (int i = 0; i < 4; ++i) s0 = dot2h(hp[i],     a0.h[i], s0);
        #pragma unroll
        for (int i = 0; i < 4; ++i) s1 = dot2h(hp[4 + i], a1.h[i], s1);
        #pragma unroll
        for (int i = 0; i < 4; ++i) s0 = dot2h(hp[8 + i], a2.h[i], s0);
        float s = red16(s0 + s1);
        if (q == 0) outg[l] = s + biasF[l];
    }
}

// ---------------- v9 LDS layout (floats) ----------------
#define V_HEXP  0        // 8192  (16384 halfs: hexp fp16)
#define V_R     8192     // 8192  (xeT fp32 4352 enc | PdL fp16 16384h dec)
#define V_GSL   16384    // 128
#define V_HCT   16512    // 256   summed hct/hctd (fp32)
#define V_SCORE 16768    // 64
#define V_AS    16832    // 64
#define V_C0    16896    // 32
#define V_C1    16928    // 32
#define V_HC1F  16960    // 256
#define V_DECIN 17216    // 64
#define V_PARTF 17280    // 256
#define V_BE0   17536    // 128 (fp32)
#define V_BE1   17664    // 128
#define V_BD0   17792    // 128
#define V_BD1   17920    // 128
#define V_AE0   18048    // 192 (384h) [x_in|h0|0]
#define V_AHH   18240    // 256 (512h) [h0|h1]
#define V_AD0   18496    // 256 (512h) [partial|h0]
#define V_HCOWN 18752    // 32  (64h)  own [h1|c1] slice
#define V_RDT   18784    // 64  (128h)
#define V_W2D   18848    // 256
#define V_TOT   19104    // x4 = 76,416 B -> 2 blocks/CU

// == v9: 8 blocks/batch x 512 thr, col-split E1/D1 folded into the h1 barrier
extern "C" __global__ void __launch_bounds__(NT8)
attn_lstm_v9(const float* __restrict__ inp,  const __half* __restrict__ wsh,
             float* __restrict__ h0x, float* __restrict__ h1x,
             float* __restrict__ hcts, float* __restrict__ hcds,
             unsigned* __restrict__ barc,
             const float* __restrict__ bihe, const float* __restrict__ bhhe,
             const float* __restrict__ bihd, const float* __restrict__ bhhd,
             const float* __restrict__ aw1,  const float* __restrict__ ab1,
             const float* __restrict__ aw2,  const float* __restrict__ db1,
             const float* __restrict__ dw2,
             const float* __restrict__ pw,   const float* __restrict__ pb,
             float* __restrict__ out)
{
    extern __shared__ __align__(16) float sm[];
    __half* hexp16 = (__half*)(sm + V_HEXP);
    float*  xeT    = sm + V_R;
    __half* PdL16  = (__half*)(sm + V_R);
    float* gsl    = sm + V_GSL;
    float* hctL   = sm + V_HCT;
    float* scoreS = sm + V_SCORE;
    float* aS     = sm + V_AS;
    float* c0L    = sm + V_C0;
    float* c1L    = sm + V_C1;
    float* hc1f   = sm + V_HC1F;
    float* decin  = sm + V_DECIN;
    float* partF  = sm + V_PARTF;
    float* bE0f   = sm + V_BE0;
    float* bE1f   = sm + V_BE1;
    float* bD0f   = sm + V_BD0;
    float* bD1f   = sm + V_BD1;
    __half* aE0   = (__half*)(sm + V_AE0);
    __half* aHH   = (__half*)(sm + V_AHH);
    __half* aD0   = (__half*)(sm + V_AD0);
    __half* hcOwn = (__half*)(sm + V_HCOWN);
    __half* rdtH  = (__half*)(sm + V_RDT);
    float* w2dL   = sm + V_W2D;

    const __half* RE0  = wsh + OFF_RE0;
    const __half* RE1  = wsh + OFF_RE1;
    const __half* RD0  = wsh + OFF_RD0;
    const __half* RD1  = wsh + OFF_RD1;
    const __half* RPD  = wsh + OFF_RPD;
    const __half* RAC  = wsh + OFF_RAC;
    const __half* RDWC = wsh + OFF_RDWC;

    const int tid = threadIdx.x;
    const int b   = blockIdx.x >> 3;
    const int co  = blockIdx.x & 7;
    const int coB = co * 32;
    const int w   = tid >> 6;
    const int lane = tid & 63;
    const int q16 = lane & 15, g4 = lane >> 4;
    const int q8l = lane & 7,  g8 = lane >> 3;
    unsigned* ctr = barc + (b << 4);
    unsigned  ph  = 0;

    // ---- init: zero misc region, stage inputs/biases/rdt/w2d ----
    for (int i = tid; i < V_TOT - V_GSL; i += NT8) sm[V_GSL + i] = 0.0f;
    const float* ib = inp + b * (64 * 65);
    for (int i = tid; i < 4096; i += NT8) {
        int t = i & 63, e = i >> 6;
        xeT[e * 68 + t] = ib[t * 65 + 1 + e];
    }
    __syncthreads();
    if (tid < 128) {
        int l = tid;
        int j = ((l & 0x60) << 3) + coB + (l & 31);
        bE0f[l] = bihe[j]        + bhhe[j];
        bE1f[l] = bihe[1024 + j] + bhhe[1024 + j];
        bD0f[l] = bihd[j]        + bhhd[j];
        bD1f[l] = bihd[1024 + j] + bhhd[1024 + j];
        rdtH[l] = wsh[OFF_RDT + j];
    }
    if (tid < 64) decin[tid] = ib[tid * 65];
    if (tid < 256) w2dL[tid] = dw2[tid];
    __syncthreads();

    // ---- encoder attention P (input part + bias, fp32 one-time) -> regs ----
    const int e8 = tid >> 3, q8 = tid & 7;
    float Preg[8], w2r[8];
    #pragma unroll
    for (int jj = 0; jj < 8; ++jj) {
        int j = q8 + 8 * jj;
        w2r[jj] = aw2[j];
        float acc = ab1[j];
        const float4* w4 = (const float4*)(aw1 + j * 576 + 512);
        const float4* x4 = (const float4*)(xeT + e8 * 68);
        #pragma unroll 4
        for (int k = 0; k < 16; ++k) acc += dot4(w4[k], x4[k]);
        Preg[jj] = acc;
    }

    // ================= encoder: 64 steps, 2 exchanges each =================
    // hctL starts zeroed (h1=c1=0 at t=0).
    for (int t = 0; t < 64; ++t) {
        const int p = t & 1;
        float* h0b = h0x + p * 16384 + b * 256;
        float* h1b = h1x + p * 16384 + b * 256;
        float* hcs = hcts + p * 32768 + b * 512 + co * 64;
        // E2: score[e] from summed hct
        {
            float s = 0.f;
            #pragma unroll
            for (int jj = 0; jj < 8; ++jj)
                s += tanhf_(Preg[jj] + hctL[q8 + 8 * jj]) * w2r[jj];
            s = red8(s);
            if (q8 == 0) scoreS[e8] = s;
        }
        __syncthreads();
        // E3: softmax + x_in
        if (tid < 64) {
            float v = scoreS[tid], m = v;
            #pragma unroll
            for (int d = 1; d < 64; d <<= 1) m = fmaxf(m, __shfl_xor(m, d));
            float ex = __expf(v - m), s = ex;
            #pragma unroll
            for (int d = 1; d < 64; d <<= 1) s += __shfl_xor(s, d);
            aE0[tid] = __float2half((ex / s) * xeT[tid * 68 + t]);
        }
        __syncthreads();
        // E4 (row-split): layer0 gates, own 128 rows
        gemvS384<4>(RE0, aE0, bE0f, gsl, coB);
        __syncthreads();
        // E5: elementwise l0 (own 32 ch) -> publish h0 slice
        if (tid < 32) {
            float cn = sigf(gsl[32 + tid]) * c0L[tid] + sigf(gsl[tid]) * tanhf_(gsl[64 + tid]);
            float hn = sigf(gsl[96 + tid]) * tanhf_(cn);
            c0L[tid] = cn;
            exw(&h0b[coB + tid], hn);
        }
        xsig(ctr); ++ph;
        xwait(ctr, ph * 8u);
        if (tid < 256) {
            __half hh = __float2half(exr(&h0b[tid]));
            aE0[64 + tid] = hh; aHH[tid] = hh;
        }
        __syncthreads();
        // E6 (row-split): layer1 gates
        gemvS512<4, true, false>(RE1, aHH, bE1f, nullptr, 0.f, gsl, coB);
        __syncthreads();
        // E7: elementwise l1 -> own h1/c1 slice; col-split hct partials;
        //     publish h1 slice + partials in ONE barrier.
        if (tid < 32) {
            float cn = sigf(gsl[32 + tid]) * c1L[tid] + sigf(gsl[tid]) * tanhf_(gsl[64 + tid]);
            float hn = sigf(gsl[96 + tid]) * tanhf_(cn);
            c1L[tid] = cn;
            hcOwn[tid] = __float2half(hn);
            hcOwn[32 + tid] = __float2half(cn);
            exw(&h1b[coB + tid], hn);
        }
        __syncthreads();   // hcOwn visible to all waves
        {   // hct partial: 64 rows x own 64 hc-cols (RAC tile)
            const int j = w * 8 + g8;
            H8 a; a.u = *(const uint4*)((const __half*)hcOwn + 8 * q8l);
            H8 wv; wv.u = *(const uint4*)(RAC + ((size_t)co << 12) + j * 64 + 8 * q8l);
            float s = 0.f;
            #pragma unroll
            for (int i = 0; i < 4; ++i) s = dot2h(wv.h[i], a.h[i], s);
            s = red8(s);
            if (q8l == 0) exw(&hcs[j], s);
        }
        xsig(ctr); ++ph;
        xwait(ctr, ph * 8u);
        if (tid < 256) {
            float v = exr(&h1b[tid]);
            __half hh = __float2half(v);
            aHH[256 + tid] = hh;
            hexp16[t * 256 + tid] = hh;
        }
        if (tid < 64) {
            const float* base = hcts + p * 32768 + b * 512;
            float s = 0.f;
            #pragma unroll
            for (int c = 0; c < 8; ++c) s += exr(base + c * 64 + tid);
            hctL[tid] = s;
        }
        __syncthreads();
    }

    // ---- transition: zero recurrent state; Pd -> LDS fp16 ----
    if (tid < 64)  sm[V_C0 + tid] = 0.0f;                 // c0L + c1L
    if (tid < 256) hctL[tid] = 0.0f;
    for (int i = tid; i < 736; i += NT8) sm[V_AE0 + i] = 0.0f;  // aE0,aHH,aD0,hcOwn
    __syncthreads();
    {
        #pragma unroll 1
        for (int it = 0; it < 8; ++it) {
            const int j = it * 32 + w * 4 + g4;
            const h2v* wp = (const h2v*)(RPD + ((size_t)j << 8) + 16 * q16);
            h2v w0 = wp[0], w1 = wp[1], w2 = wp[2], w3 = wp[3];
            h2v w4 = wp[4], w5 = wp[5], w6 = wp[6], w7 = wp[7];
            float dbj = db1[j];
            #pragma unroll 2
            for (int tp = 0; tp < 64; ++tp) {
                const h2v* xp = (const h2v*)(hexp16 + tp * 256 + 8 * q16);
                const h2v* yp = (const h2v*)(hexp16 + tp * 256 + 8 * q16 + 128);
                float s = 0.f;
                s = dot2h(w0, xp[0], s); s = dot2h(w1, xp[1], s);
                s = dot2h(w2, xp[2], s); s = dot2h(w3, xp[3], s);
                s = dot2h(w4, yp[0], s); s = dot2h(w5, yp[1], s);
                s = dot2h(w6, yp[2], s); s = dot2h(w7, yp[3], s);
                s = red16(s);
                if (q16 == 0) PdL16[tp * 256 + j] = __float2half(s + dbj);
            }
        }
    }
    __syncthreads();

    // ============ decoder: 64 steps, 2 exchanges each ============
    for (int t = 0; t < 64; ++t) {
        const int p = t & 1;
        float* h0b = h0x + p * 16384 + b * 256;
        float* h1b = h1x + p * 16384 + b * 256;
        float* hcd = hcds + p * 131072 + b * 2048 + co * 256;
        // D2: score[t'] from summed hctd (zero at t=0)
        {
            float s = 0.f;
            #pragma unroll 8
            for (int jj = 0; jj < 32; ++jj) {
                int j = q8 + 8 * jj;
                s += tanhf_((float)PdL16[e8 * 256 + j] + hctL[j]) * w2dL[j];
            }
            s = red8(s);
            if (q8 == 0) scoreS[e8] = s;
        }
        __syncthreads();
        // D3: softmax -> aS
        if (tid < 64) {
            float v = scoreS[tid], m = v;
            #pragma unroll
            for (int d = 1; d < 64; d <<= 1) m = fmaxf(m, __shfl_xor(m, d));
            float ex = __expf(v - m), s = ex;
            #pragma unroll
            for (int d = 1; d < 64; d <<= 1) s += __shfl_xor(s, d);
            aS[tid] = ex / s;
        }
        __syncthreads();
        // D4 (replicated): partial[c]
        if (tid < 256) {
            float acc = 0.f;
            #pragma unroll 8
            for (int tt = 0; tt < 64; ++tt)
                acc += (float)hexp16[tt * 256 + tid] * aS[tt];
            partF[tid] = acc;
            aD0[tid] = __float2half(acc);
        }
        __syncthreads();
        // D5 (row-split): layer0 gates (+ d_t column)
        gemvS512<4, true, true>(RD0, aD0, bD0f, rdtH, decin[t], gsl, coB);
        __syncthreads();
        // D6: elementwise l0 -> publish h0 slice
        if (tid < 32) {
            float cn = sigf(gsl[32 + tid]) * c0L[tid] + sigf(gsl[tid]) * tanhf_(gsl[64 + tid]);
            float hn = sigf(gsl[96 + tid]) * tanhf_(cn);
            c0L[tid] = cn;
            exw(&h0b[coB + tid], hn);
        }
        xsig(ctr); ++ph;
        xwait(ctr, ph * 8u);
        if (tid < 256) {
            __half hh = __float2half(exr(&h0b[tid]));
            aD0[256 + tid] = hh; aHH[tid] = hh;
        }
        __syncthreads();
        // D7 (row-split): layer1 gates
        gemvS512<4, true, false>(RD1, aHH, bD1f, nullptr, 0.f, gsl, coB);
        __syncthreads();
        // D8: elementwise l1 -> own h1/c1; col-split hctd partials (RDWC);
        //     publish h1 slice + 256 partials in ONE barrier (D1 folded).
        if (tid < 32) {
            float cn = sigf(gsl[32 + tid]) * c1L[tid] + sigf(gsl[tid]) * tanhf_(gsl[64 + tid]);
            float hn = sigf(gsl[96 + tid]) * tanhf_(cn);
            c1L[tid] = cn;
            hcOwn[tid] = __float2half(hn);
            hcOwn[32 + tid] = __float2half(cn);
            exw(&h1b[coB + tid], hn);
        }
        __syncthreads();
        {   // hctd partials: 256 rows x own 64 hc-cols (RDWC tile)
            H8 a; a.u = *(const uint4*)((const __half*)hcOwn + 8 * q8l);
            #pragma unroll
            for (int it = 0; it < 4; ++it) {
                const int j = it * 64 + w * 8 + g8;
                H8 wv; wv.u = *(const uint4*)(RDWC + ((size_t)co << 14) + j * 64 + 8 * q8l);
                float s = 0.f;
                #pragma unroll
                for (int i = 0; i < 4; ++i) s = dot2h(wv.h[i], a.h[i], s);
                s = red8(s);
                if (q8l == 0) exw(&hcd[j], s);
            }
        }
        xsig(ctr); ++ph;
        xwait(ctr, ph * 8u);
        if (tid < 256) {
            float v = exr(&h1b[tid]);
            aHH[256 + tid] = __float2half(v);
            hc1f[tid] = v;
            const float* base = hcds + p * 131072 + b * 2048;
            float s = 0.f;
            #pragma unroll
            for (int c = 0; c < 8; ++c) s += exr(base + c * 256 + tid);
            hctL[tid] = s;
        }
        __syncthreads();
    }

    // ---- output (one block per b) ----
    if (co == 0 && tid < 64) {
        float acc = 0.f;
        #pragma unroll
        for (int i = 0; i < 8; ++i) {
            int k = tid + 64 * i;
            float v = (k < 256) ? hc1f[k] : partF[k - 256];
            acc += v * pw[k];
        }
        acc = red64(acc);
        if (tid == 0) out[b] = fabsf(acc + pb[0]);
    }
}

// ---- fp16 permuted repack (v8 layout + RAC/RDWC column tiles) ----
extern "C" __global__ void repack16d(const float* __restrict__ wihe0,
                                     const float* __restrict__ wihe1,
                                     const float* __restrict__ whhe,
                                     const float* __restrict__ wihd0,
                                     const float* __restrict__ wihd1,
                                     const float* __restrict__ whhd,
                                     const float* __restrict__ aw1,
                                     const float* __restrict__ dw1,
                                     __half* __restrict__ ws) {
    int idx = blockIdx.x * blockDim.x + threadIdx.x;
    if (idx >= TOT_H3) return;
    int o = idx; float v;
    if (o < 32768) {                       // RA (v5 fallback)
        int j = o >> 9, p = o & 511;
        int q = p >> 5, r = p & 31, c = r >> 3, e = r & 7;
        int k = 8 * q + 128 * c + e;
        v = aw1[j * 576 + k];
        ws[OFF_RA + o] = __float2half_rn(v); return;
    }
    o -= 32768;
    if (o < 393216) {                      // RE0
        int j = o / 384, p = o - j * 384;
        int q = p / 24, r = p - q * 24, c = r >> 3, e = r & 7;
        int k = 8 * q + 128 * c + e;
        v = (k < 64) ? wihe0[j * 64 + k] : (k < 320 ? whhe[j * 256 + (k - 64)] : 0.0f);
        ws[OFF_RE0 + o] = __float2half_rn(v); return;
    }
    o -= 393216;
    if (o < 524288) {                      // RE1
        int j = o >> 9, p = o & 511;
        int q = p >> 5, r = p & 31, c = r >> 3, e = r & 7;
        int k = 8 * q + 128 * c + e;
        v = (k < 256) ? wihe1[j * 256 + k] : whhe[262144 + j * 256 + (k - 256)];
        ws[OFF_RE1 + o] = __float2half_rn(v); return;
    }
    o -= 524288;
    if (o < 131072) {                      // RDW1 (v5 fallback)
        int j = o >> 9, p = o & 511;
        int q = p >> 5, r = p & 31, c = r >> 3, e = r & 7;
        int k = 8 * q + 128 * c + e;
        v = dw1[j * 768 + k];
        ws[OFF_RDW1 + o] = __float2half_rn(v); return;
    }
    o -= 131072;
    if (o < 524288) {                      // RD0
        int j = o >> 9, p = o & 511;
        int q = p >> 5, r = p & 31, c = r >> 3, e = r & 7;
        int k = 8 * q + 128 * c + e;
        v = (k < 256) ? wihd0[j * 257 + k] : whhd[j * 256 + (k - 256)];
        ws[OFF_RD0 + o] = __float2half_rn(v); return;
    }
    o -= 524288;
    if (o < 1024) {                        // RDT
        v = wihd0[o * 257 + 256];
        ws[OFF_RDT + o] = __float2half_rn(v); return;
    }
    o -= 1024;
    if (o < 524288) {                      // RD1
        int j = o >> 9, p = o & 511;
        int q = p >> 5, r = p & 31, c = r >> 3, e = r & 7;
        int k = 8 * q + 128 * c + e;
        v = (k < 256) ? wihd1[j * 256 + k] : whhd[262144 + j * 256 + (k - 256)];
        ws[OFF_RD1 + o] = __float2half_rn(v); return;
    }
    o -= 524288;
    if (o < 65536) {                       // RPD
        int j = o >> 8, p = o & 255;
        int q = p >> 4, r = p & 15, c = r >> 3, e = r & 7;
        int k = 8 * q + 128 * c + e;
        v = dw1[j * 768 + 512 + k];
        ws[OFF_RPD + o] = __float2half_rn(v); return;
    }
    o -= 65536;
    if (o < 32768) {                       // RAC: [co][j<64][k<64]
        int c8 = o >> 12, r12 = o & 4095, j = r12 >> 6, k = r12 & 63;
        int col = (k < 32) ? (c8 * 32 + k) : (256 + c8 * 32 + (k - 32));
        v = aw1[j * 576 + col];
        ws[OFF_RAC + o] = __float2half_rn(v); return;
    }
    o -= 32768;
    {                                      // RDWC: [co][j<256][k<64]
        int c8 = o >> 14, r14 = o & 16383, j = r14 >> 6, k = r14 & 63;
        int col = (k < 32) ? (c8 * 32 + k) : (256 + c8 * 32 + (k - 32));
        v = dw1[j * 768 + col];
        ws[OFF_RDWC + o] = __float2half_rn(v);
    }
}

// ======================= v5 fallback (tiny ws) =============================
template<int ITERS, bool BIAS, bool DT>
__device__ __forceinline__ void gemv512f(const __half* __restrict__ W,
                                         const __half* __restrict__ act,
                                         const float* __restrict__ bias,
                                         const __half* __restrict__ rdt, float dts,
                                         float* __restrict__ outg, int rowBase) {
    const int lane = threadIdx.x & 63;
    const int q = lane & 15, g = lane >> 4;
    H8 a0, a1, a2, a3;
    a0.u = *(const uint4*)(act + 8 * q);
    a1.u = *(const uint4*)(act + 8 * q + 128);
    a2.u = *(const uint4*)(act + 8 * q + 256);
    a3.u = *(const uint4*)(act + 8 * q + 384);
    #pragma unroll 2
    for (int it = 0; it < ITERS; ++it) {
        const int j = rowBase + it * 4 + g;
        const uint4* wp = (const uint4*)(W + ((size_t)j << 9) + 32 * q);
        H8 w0, w1, w2, w3;
        w0.u = wp[0]; w1.u = wp[1]; w2.u = wp[2]; w3.u = wp[3];
        float s0 = 0.f, s1 = 0.f;
        #pragma unroll
        for (int i = 0; i < 4; ++i) {
            s0 = dot2h(w0.h[i], a0.h[i], s0);
            s1 = dot2h(w1.h[i], a1.h[i], s1);
            s0 = dot2h(w2.h[i], a2.h[i], s0);
            s1 = dot2h(w3.h[i], a3.h[i], s1);
        }
        float s = red16(s0 + s1);
        if (q == 0) {
            if (DT) s += dts * (float)rdt[j];
            outg[j] = BIAS ? s + bias[j] : s;
        }
    }
}
template<int ITERS>
__device__ __forceinline__ void gemv384f(const __half* __restrict__ W,
                                         const __half* __restrict__ act,
                                         const float* __restrict__ bias,
                                         float* __restrict__ outg, int rowBase) {
    const int lane = threadIdx.x & 63;
    const int q = lane & 15, g = lane >> 4;
    H8 a0, a1, a2;
    a0.u = *(const uint4*)(act + 8 * q);
    a1.u = *(const uint4*)(act + 8 * q + 128);
    a2.u = *(const uint4*)(act + 8 * q + 256);
    #pragma unroll 2
    for (int it = 0; it < ITERS; ++it) {
        const int j = rowBase + it * 4 + g;
        const h2v* hp = (const h2v*)(W + (size_t)j * 384 + 24 * q);
        float s0 = 0.f, s1 = 0.f;
        #pragma unroll
        for (int i = 0; i < 4; ++i) s0 = dot2h(hp[i],     a0.h[i], s0);
        #pragma unroll
        for (int i = 0; i < 4; ++i) s1 = dot2h(hp[4 + i], a1.h[i], s1);
        #pragma unroll
        for (int i = 0; i < 4; ++i) s0 = dot2h(hp[8 + i], a2.h[i], s0);
        float s = red16(s0 + s1);
        if (q == 0) outg[j] = s + bias[j];
    }
}

#define L_HEXP   0
#define L_XET    16384
#define L_GSL    20736
#define L_HCT    21760
#define L_SCORE  22016
#define L_AS     22080
#define L_C0     22144
#define L_HC1F   22400
#define L_DECIN  22912
#define L_PARTF  22976
#define L_BE0    23232
#define L_BE1    24256
#define L_BD0    25280
#define L_BD1    26304
#define L_AHC    27328
#define L_AE0    27584
#define L_AHH    27776
#define L_AD0    28032
#define L_RDT    28288
#define L_TOT    28800

extern "C" __global__ void __launch_bounds__(NT)
attn_lstm_v5(const float* __restrict__ inp,  const __half* __restrict__ wsh,
             const float* __restrict__ bihe, const float* __restrict__ bhhe,
             const float* __restrict__ bihd, const float* __restrict__ bhhd,
             const float* __restrict__ aw1,  const float* __restrict__ ab1,
             const float* __restrict__ aw2,
             const float* __restrict__ dw1,  const float* __restrict__ db1,
             const float* __restrict__ dw2,
             const float* __restrict__ pw,   const float* __restrict__ pb,
             float* __restrict__ out)
{
    extern __shared__ __align__(16) float sm[];
    float* hexp   = sm + L_HEXP;
    float* xeT    = sm + L_XET;
    float* gsl    = sm + L_GSL;
    float* hctL   = sm + L_HCT;
    float* scoreS = sm + L_SCORE;
    float* aS     = sm + L_AS;
    float* c0L    = sm + L_C0;
    float* hc1f   = sm + L_HC1F;
    float* decin  = sm + L_DECIN;
    float* partF  = sm + L_PARTF;
    float* bE0    = sm + L_BE0;
    float* bE1    = sm + L_BE1;
    float* bD0    = sm + L_BD0;
    float* bD1    = sm + L_BD1;
    __half* aHC   = (__half*)(sm + L_AHC);
    __half* aE0   = (__half*)(sm + L_AE0);
    __half* aHH   = (__half*)(sm + L_AHH);
    __half* aD0   = (__half*)(sm + L_AD0);
    __half* rdtL  = (__half*)(sm + L_RDT);

    const __half* RA   = wsh + OFF_RA;
    const __half* RE0  = wsh + OFF_RE0;
    const __half* RE1  = wsh + OFF_RE1;
    const __half* RDW1 = wsh + OFF_RDW1;
    const __half* RD0  = wsh + OFF_RD0;
    const __half* RD1  = wsh + OFF_RD1;

    const int b   = blockIdx.x;
    const int tid = threadIdx.x;
    const int w   = tid >> 6;

    for (int i = tid; i < (L_BE0 - L_C0); i += NT) sm[L_C0 + i] = 0.0f;
    for (int i = tid; i < (L_RDT - L_AHC); i += NT) sm[L_AHC + i] = 0.0f;
    if (tid < 512) sm[L_RDT + tid] = ((const float*)(wsh + OFF_RDT))[tid];
    {
        int j = tid;
        bE0[j] = bihe[j]        + bhhe[j];
        bE1[j] = bihe[1024 + j] + bhhe[1024 + j];
        bD0[j] = bihd[j]        + bhhd[j];
        bD1[j] = bihd[1024 + j] + bhhd[1024 + j];
    }
    const float* ib = inp + b * (64 * 65);
    for (int i = tid; i < 4096; i += NT) {
        int t = i & 63, e = i >> 6;
        xeT[e * 68 + t] = ib[t * 65 + 1 + e];
    }
    if (tid < 64) decin[tid] = ib[tid * 65];
    __syncthreads();

    const int g16 = tid >> 4, q16 = tid & 15;

    float Preg[4], w2r[4];
    #pragma unroll
    for (int jj = 0; jj < 4; ++jj) {
        int j = q16 + 16 * jj;
        w2r[jj] = aw2[j];
        float acc = ab1[j];
        const float4* w4 = (const float4*)(aw1 + j * 576 + 512);
        const float4* x4 = (const float4*)(xeT + g16 * 68);
        #pragma unroll 4
        for (int k = 0; k < 16; ++k) acc += dot4(w4[k], x4[k]);
        Preg[jj] = acc;
    }

    for (int t = 0; t < 64; ++t) {
        gemv512f<1, false, false>(RA, aHC, nullptr, nullptr, 0.f, hctL, w * 4);
        __syncthreads();
        {
            float s = 0.f;
            #pragma unroll
            for (int jj = 0; jj < 4; ++jj)
                s += tanhf_(Preg[jj] + hctL[q16 + 16 * jj]) * w2r[jj];
            s = red16(s);
            if (q16 == 0) scoreS[g16] = s;
        }
        __syncthreads();
        if (tid < 64) {
            float v = scoreS[tid], m = v;
            #pragma unroll
            for (int d = 1; d < 64; d <<= 1) m = fmaxf(m, __shfl_xor(m, d));
            float ex = __expf(v - m), s = ex;
            #pragma unroll
            for (int d = 1; d < 64; d <<= 1) s += __shfl_xor(s, d);
            aE0[tid] = __float2half((ex / s) * xeT[tid * 68 + t]);
        }
        __syncthreads();
        gemv384f<16>(RE0, aE0, bE0, gsl, w * 64);
        __syncthreads();
        if (tid < 256) {
            float cn = sigf(gsl[256 + tid]) * c0L[tid] + sigf(gsl[tid]) * tanhf_(gsl[512 + tid]);
            float hn = sigf(gsl[768 + tid]) * tanhf_(cn);
            c0L[tid] = cn;
            __half hh = __float2half(hn);
            aE0[64 + tid] = hh; aHH[tid] = hh;
        }
        __syncthreads();
        gemv512f<16, true, false>(RE1, aHH, bE1, nullptr, 0.f, gsl, w * 64);
        __syncthreads();
        if (tid < 256) {
            float cp = hc1f[256 + tid];
            float cn = sigf(gsl[256 + tid]) * cp + sigf(gsl[tid]) * tanhf_(gsl[512 + tid]);
            float hn = sigf(gsl[768 + tid]) * tanhf_(cn);
            hc1f[tid] = hn; hc1f[256 + tid] = cn;
            __half hh = __float2half(hn);
            aHC[tid] = hh; aHC[256 + tid] = __float2half(cn);
            aHH[256 + tid] = hh;
            hexp[t * 256 + tid] = hn;
        }
        __syncthreads();
    }

    if (tid < 256) { c0L[tid] = 0.0f; hc1f[tid] = 0.0f; hc1f[256 + tid] = 0.0f; }
    for (int i = tid; i < (L_RDT - L_AHC); i += NT) sm[L_AHC + i] = 0.0f;
    __syncthreads();
    float Pdreg[16], w2dr[16];
    #pragma unroll
    for (int jj = 0; jj < 16; ++jj) {
        int j = q16 + 16 * jj;
        w2dr[jj] = dw2[j];
        float acc = db1[j];
        const float4* w4 = (const float4*)(dw1 + j * 768 + 512);
        const float4* x4 = (const float4*)(hexp + g16 * 256);
        #pragma unroll 4
        for (int k = 0; k < 64; ++k) acc += dot4(w4[k], x4[k]);
        Pdreg[jj] = acc;
    }
    __syncthreads();

    const int j4 = tid >> 2, q4 = tid & 3;
    for (int t = 0; t < 64; ++t) {
        gemv512f<4, false, false>(RDW1, aHC, nullptr, nullptr, 0.f, hctL, w * 16);
        __syncthreads();
        {
            float s = 0.f;
            #pragma unroll
            for (int jj = 0; jj < 16; ++jj)
                s += tanhf_(Pdreg[jj] + hctL[q16 + 16 * jj]) * w2dr[jj];
            s = red16(s);
            if (q16 == 0) scoreS[g16] = s;
        }
        __syncthreads();
        if (tid < 64) {
            float v = scoreS[tid], m = v;
            #pragma unroll
            for (int d = 1; d < 64; d <<= 1) m = fmaxf(m, __shfl_xor(m, d));
            float ex = __expf(v - m), s = ex;
            #pragma unroll
            for (int d = 1; d < 64; d <<= 1) s += __shfl_xor(s, d);
            aS[tid] = ex / s;
        }
        __syncthreads();
        {
            float acc = 0.f;
            #pragma unroll 4
            for (int i = 0; i < 16; ++i) {
                int tt = q4 + 4 * i;
                acc += hexp[tt * 256 + j4] * aS[tt];
            }
            acc += __shfl_xor(acc, 1);
            acc += __shfl_xor(acc, 2);
            if (q4 == 0) { aD0[j4] = __float2half(acc); partF[j4] = acc; }
        }
        __syncthreads();
        gemv512f<16, true, true>(RD0, aD0, bD0, rdtL, decin[t], gsl, w * 64);
        __syncthreads();
        if (tid < 256) {
            float cn = sigf(gsl[256 + tid]) * c0L[tid] + sigf(gsl[tid]) * tanhf_(gsl[512 + tid]);
            float hn = sigf(gsl[768 + tid]) * tanhf_(cn);
            c0L[tid] = cn;
            __half hh = __float2half(hn);
            aD0[256 + tid] = hh; aHH[tid] = hh;
        }
        __syncthreads();
        gemv512f<16, true, false>(RD1, aHH, bD1, nullptr, 0.f, gsl, w * 64);
        __syncthreads();
        if (tid < 256) {
            float cp = hc1f[256 + tid];
            float cn = sigf(gsl[256 + tid]) * cp + sigf(gsl[tid]) * tanhf_(gsl[512 + tid]);
            float hn = sigf(gsl[768 + tid]) * tanhf_(cn);
            hc1f[tid] = hn; hc1f[256 + tid] = cn;
            __half hh = __float2half(hn);
            aHC[tid] = hh; aHC[256 + tid] = __float2half(cn);
            aHH[256 + tid] = hh;
        }
        __syncthreads();
    }

    if (tid < 64) {
        float acc = 0.f;
        #pragma unroll
        for (int i = 0; i < 8; ++i) {
            int k = tid + 64 * i;
            float v = (k < 256) ? hc1f[k] : partF[k - 256];
            acc += v * pw[k];
        }
        acc = red64(acc);
        if (tid == 0) out[b] = fabsf(acc + pb[0]);
    }
}

extern "C" void kernel_launch(void* const* d_in, const int* in_sizes, int n_in,
                              void* d_out, int out_size, void* d_ws, size_t ws_size,
                              hipStream_t stream) {
    const float* inp   = (const float*)d_in[0];
    const float* wihe0 = (const float*)d_in[1];
    const float* wihe1 = (const float*)d_in[2];
    const float* whhe  = (const float*)d_in[3];
    const float* bihe  = (const float*)d_in[4];
    const float* bhhe  = (const float*)d_in[5];
    const float* wihd0 = (const float*)d_in[6];
    const float* wihd1 = (const float*)d_in[7];
    const float* whhd  = (const float*)d_in[8];
    const float* bihd  = (const float*)d_in[9];
    const float* bhhd  = (const float*)d_in[10];
    const float* aw1   = (const float*)d_in[11];
    const float* ab1   = (const float*)d_in[12];
    const float* aw2   = (const float*)d_in[13];
    const float* dw1   = (const float*)d_in[14];
    const float* db1   = (const float*)d_in[15];
    const float* dw2   = (const float*)d_in[16];
    const float* pw    = (const float*)d_in[17];
    const float* pb    = (const float*)d_in[18];
    float* out = (float*)d_out;

    // ws layout (float offsets): fp16 weights occupy [0, TOT_H3/2)
    const size_t WH   = TOT_H3 / 2;          // 1,180,160
    const size_t H0X  = WH;                  // 2*64*256 = 32768 (h0 broadcast)
    const size_t H1X  = WH + 32768;          // 2*64*256 = 32768 (h1 broadcast)
    const size_t HCTS = WH + 65536;          // 2*64*8*64  = 65536 (enc partials)
    const size_t HCDS = WH + 131072;         // 2*64*8*256 = 262144 (dec partials)
    const size_t CTR  = WH + 393216;         // 64 groups * 16 uints
    const size_t NEED9 = (CTR + 1024) * sizeof(float);   // ~6.3 MB

    if (ws_size >= NEED9) {
        float* ws32 = (float*)d_ws;
        __half* wsh = (__half*)d_ws;
        hipMemsetAsync((char*)d_ws + CTR * sizeof(float), 0, 4096, stream);
        repack16d<<<(TOT_H3 + 255) / 256, 256, 0, stream>>>(
            wihe0, wihe1, whhe, wihd0, wihd1, whhd, aw1, dw1, wsh);
        const int smem = V_TOT * 4;   // 76,416 B -> 2 blocks/CU
        hipFuncSetAttribute((const void*)attn_lstm_v9,
                            hipFuncAttributeMaxDynamicSharedMemorySize, smem);
        attn_lstm_v9<<<512, NT8, smem, stream>>>(
            inp, wsh, ws32 + H0X, ws32 + H1X, ws32 + HCTS, ws32 + HCDS,
            (unsigned*)(ws32 + CTR),
            bihe, bhhe, bihd, bhhd,
            aw1, ab1, aw2, db1, dw2, pw, pb, out);
        return;
    }

    // fallback: v5 single-block-per-batch (needs only the weight region)
    if (ws_size >= (size_t)TOT_H3 * sizeof(__half)) {
        __half* wsh = (__half*)d_ws;
        repack16d<<<(TOT_H3 + 255) / 256, 256, 0, stream>>>(
            wihe0, wihe1, whhe, wihd0, wihd1, whhd, aw1, dw1, wsh);
        const int smem = L_TOT * 4;
        hipFuncSetAttribute((const void*)attn_lstm_v5,
                            hipFuncAttributeMaxDynamicSharedMemorySize, smem);
        attn_lstm_v5<<<64, NT, smem, stream>>>(
            inp, wsh, bihe, bhhe, bihd, bhhd,
            aw1, ab1, aw2, dw1, db1, dw2, pw, pb, out);
    }
}